// Round 1
// baseline (4194.323 us; speedup 1.0000x reference)
//
#include <hip/hip_runtime.h>
#include <math.h>

#define NN 100000
#define NE 1600000
#define DH 128

// ---------------- degree / dinv ----------------
__global__ __launch_bounds__(256) void k_init_deg(float* __restrict__ deg) {
  int i = blockIdx.x * 256 + threadIdx.x;
  if (i < NN) deg[i] = 1.0f;  // self loop
}

__global__ __launch_bounds__(256) void k_count(const int* __restrict__ dst, float* __restrict__ deg) {
  int e = blockIdx.x * 256 + threadIdx.x;
  if (e < NE) atomicAdd(&deg[dst[e]], 1.0f);
}

__global__ __launch_bounds__(256) void k_rsqrt(float* __restrict__ deg) {
  int i = blockIdx.x * 256 + threadIdx.x;
  if (i < NN) deg[i] = rsqrtf(deg[i]);
}

// ---------------- GEMM: Y[r][c] = sum_k X[r][k] * W[k][c], K=C=128 ----------------
// block: 256 threads, 64 rows/block. W staged fully in LDS (64KB).
__global__ __launch_bounds__(256) void k_gemm128(const float* __restrict__ X,
                                                 const float* __restrict__ W,
                                                 float* __restrict__ Y, int nrows) {
  __shared__ float Wl[128 * 128];
  const float4* W4 = (const float4*)W;
  float4* Wl4 = (float4*)Wl;
#pragma unroll
  for (int i = 0; i < 16; ++i) Wl4[threadIdx.x + i * 256] = W4[threadIdx.x + i * 256];
  __syncthreads();

  const int tc = threadIdx.x & 15;   // col group
  const int tr = threadIdx.x >> 4;   // row group
  const int r0 = blockIdx.x * 64 + tr * 4;
  const int c0 = tc * 8;

  float acc[4][8];
#pragma unroll
  for (int i = 0; i < 4; ++i)
#pragma unroll
    for (int j = 0; j < 8; ++j) acc[i][j] = 0.f;

  for (int k0 = 0; k0 < 128; k0 += 4) {
    float4 xv[4];
#pragma unroll
    for (int i = 0; i < 4; ++i) {
      int r = r0 + i;
      xv[i] = (r < nrows) ? *(const float4*)(X + (size_t)r * 128 + k0)
                          : make_float4(0.f, 0.f, 0.f, 0.f);
    }
#pragma unroll
    for (int kk = 0; kk < 4; ++kk) {
      float4 wa = *(const float4*)(Wl + (k0 + kk) * 128 + c0);
      float4 wb = *(const float4*)(Wl + (k0 + kk) * 128 + c0 + 4);
      float wv[8] = {wa.x, wa.y, wa.z, wa.w, wb.x, wb.y, wb.z, wb.w};
#pragma unroll
      for (int i = 0; i < 4; ++i) {
        float xs = reinterpret_cast<const float*>(&xv[i])[kk];
#pragma unroll
        for (int j = 0; j < 8; ++j) acc[i][j] = fmaf(xs, wv[j], acc[i][j]);
      }
    }
  }

#pragma unroll
  for (int i = 0; i < 4; ++i) {
    int r = r0 + i;
    if (r < nrows) {
      float4 oa = make_float4(acc[i][0], acc[i][1], acc[i][2], acc[i][3]);
      float4 ob = make_float4(acc[i][4], acc[i][5], acc[i][6], acc[i][7]);
      *(float4*)(Y + (size_t)r * 128 + c0) = oa;
      *(float4*)(Y + (size_t)r * 128 + c0 + 4) = ob;
    }
  }
}

// ---------------- agg init: AGG[i][c] = dinv[i]^2 * H[i][c] (self-loop term) ----------------
__global__ __launch_bounds__(256) void k_init_agg(float* __restrict__ AGG,
                                                   const float* __restrict__ H,
                                                   const float* __restrict__ dinv) {
  int gid = blockIdx.x * 256 + threadIdx.x;  // over NN*32 float4s
  int node = gid >> 5;
  if (node >= NN) return;
  float w = dinv[node];
  w *= w;
  float4 v = ((const float4*)H)[gid];
  ((float4*)AGG)[gid] = make_float4(v.x * w, v.y * w, v.z * w, v.w * w);
}

// ---------------- edge scatter: AGG[d] += dinv[s]*dinv[d] * H[s], one wave per edge ----------------
__global__ __launch_bounds__(256) void k_scatter(const float* __restrict__ H,
                                                  float* __restrict__ AGG,
                                                  const float* __restrict__ dinv,
                                                  const int* __restrict__ src,
                                                  const int* __restrict__ dst) {
  int gid = blockIdx.x * 256 + threadIdx.x;
  int e = gid >> 6;
  int lane = threadIdx.x & 63;
  if (e >= NE) return;
  int s = src[e], d = dst[e];
  float w = dinv[s] * dinv[d];
  float2 v = ((const float2*)(H + (size_t)s * 128))[lane];
  float* a = AGG + (size_t)d * 128 + lane * 2;
  atomicAdd(a, w * v.x);
  atomicAdd(a + 1, w * v.y);
}

// ---------------- finish: H[i][c] = relu(AGG[i][c] + b[c]) in place ----------------
__global__ __launch_bounds__(256) void k_finish(float* __restrict__ AGG, const float* __restrict__ b) {
  int gid = blockIdx.x * 256 + threadIdx.x;
  int node = gid >> 5;
  if (node >= NN) return;
  int c4 = (gid & 31) * 4;
  float4 v = ((float4*)AGG)[gid];
  float4 bb = *(const float4*)(b + c4);
  v.x = fmaxf(v.x + bb.x, 0.f);
  v.y = fmaxf(v.y + bb.y, 0.f);
  v.z = fmaxf(v.z + bb.z, 0.f);
  v.w = fmaxf(v.w + bb.w, 0.f);
  ((float4*)AGG)[gid] = v;
}

// ---------------- edge MLP ----------------
// out[e] = sigmoid( relu([H[src],H[dst]] @ Wm1 + bm1) @ Wm2 + bm2 )
// block: 256 threads, TILE_E=64 edges. k-chunked (4 chunks of 64).
// thread tile: 4 edges x 8 cols. LDS: EF 64x68 (17.4KB) + WL 64x132 (33.8KB) -> 3 blocks/CU.
__global__ __launch_bounds__(256) void k_edge_mlp(const float* __restrict__ H,
                                                   const int* __restrict__ src,
                                                   const int* __restrict__ dst,
                                                   const float* __restrict__ Wm1,
                                                   const float* __restrict__ bm1,
                                                   const float* __restrict__ Wm2,
                                                   const float* __restrict__ bm2,
                                                   float* __restrict__ out) {
  __shared__ float EF[64][68];
  __shared__ float WL[64][132];

  const int tc = threadIdx.x & 15;  // col group: c0 = tc*8
  const int te = threadIdx.x >> 4;  // edge group: e0 = te*4
  const int c0 = tc * 8;
  const int e_base = blockIdx.x * 64;

  float wm2[8], bb[8];
#pragma unroll
  for (int j = 0; j < 8; ++j) {
    wm2[j] = Wm2[c0 + j];
    bb[j] = bm1[c0 + j];
  }

  float acc[4][8];
#pragma unroll
  for (int i = 0; i < 4; ++i)
#pragma unroll
    for (int j = 0; j < 8; ++j) acc[i][j] = 0.f;

#pragma unroll
  for (int c = 0; c < 4; ++c) {
    // stage EF chunk: 64 edges x 64 k  (k global = c*64 + kk)
    const int* nd = (c < 2) ? src : dst;
    const int colbase = (c & 1) * 64;
#pragma unroll
    for (int i = 0; i < 4; ++i) {
      int id = threadIdx.x + i * 256;  // 0..1023
      int e = id >> 4;
      int q = id & 15;
      int node = nd[e_base + e];
      float4 v = *(const float4*)(H + (size_t)node * 128 + colbase + q * 4);
      *(float4*)(&EF[e][q * 4]) = v;
    }
    // stage W chunk: rows c*64+kk, all 128 cols
#pragma unroll
    for (int i = 0; i < 8; ++i) {
      int id = threadIdx.x + i * 256;  // 0..2047
      int kk = id >> 5;
      int c4 = id & 31;
      float4 v = *(const float4*)(Wm1 + (size_t)(c * 64 + kk) * 128 + c4 * 4);
      *(float4*)(&WL[kk][c4 * 4]) = v;
    }
    __syncthreads();

#pragma unroll 4
    for (int kk = 0; kk < 64; ++kk) {
      float4 wa = *(const float4*)(&WL[kk][c0]);
      float4 wb = *(const float4*)(&WL[kk][c0 + 4]);
      float wv[8] = {wa.x, wa.y, wa.z, wa.w, wb.x, wb.y, wb.z, wb.w};
#pragma unroll
      for (int i = 0; i < 4; ++i) {
        float xs = EF[te * 4 + i][kk];
#pragma unroll
        for (int j = 0; j < 8; ++j) acc[i][j] = fmaf(xs, wv[j], acc[i][j]);
      }
    }
    __syncthreads();
  }

  // epilogue: z = relu(acc + bm1), partial = z . Wm2[c0..c0+7], reduce over 16 lanes
  float partial[4];
#pragma unroll
  for (int i = 0; i < 4; ++i) {
    float p = 0.f;
#pragma unroll
    for (int j = 0; j < 8; ++j) {
      float z = fmaxf(acc[i][j] + bb[j], 0.f);
      p = fmaf(z, wm2[j], p);
    }
    partial[i] = p;
  }
#pragma unroll
  for (int m = 1; m < 16; m <<= 1) {
#pragma unroll
    for (int i = 0; i < 4; ++i) partial[i] += __shfl_xor(partial[i], m, 64);
  }
  if (tc == 0) {
    float b2 = bm2[0];
#pragma unroll
    for (int i = 0; i < 4; ++i) {
      int e = e_base + te * 4 + i;
      float logit = partial[i] + b2;
      out[e] = 1.f / (1.f + expf(-logit));
    }
  }
}

// ---------------- launch ----------------
extern "C" void kernel_launch(void* const* d_in, const int* in_sizes, int n_in,
                              void* d_out, int out_size, void* d_ws, size_t ws_size,
                              hipStream_t stream) {
  const float* x   = (const float*)d_in[0];
  const int* ei    = (const int*)d_in[1];
  const float* W1  = (const float*)d_in[2];
  const float* b1  = (const float*)d_in[3];
  const float* W2  = (const float*)d_in[4];
  const float* b2  = (const float*)d_in[5];
  const float* Wm1 = (const float*)d_in[6];
  const float* bm1 = (const float*)d_in[7];
  const float* Wm2 = (const float*)d_in[8];
  const float* bm2 = (const float*)d_in[9];
  float* out = (float*)d_out;

  const int* src = ei;
  const int* dst = ei + NE;

  char* ws = (char*)d_ws;
  float* dinv = (float*)ws;                            // NN floats = 400000 B
  float* buf0 = (float*)(ws + 400000);                 // NN*128 floats = 51.2 MB
  float* buf1 = (float*)(ws + 400000 + 51200000);      // NN*128 floats = 51.2 MB

  const int gN = (NN + 255) / 256;          // 391
  const int gE = (NE + 255) / 256;          // 6250
  const int gRow = (NN + 63) / 64;          // 1563
  const int gNode4 = (NN * 32 + 255) / 256; // 12500
  const int gScat = NE / 4;                 // 400000 (exact)
  const int gMlp = NE / 64;                 // 25000 (exact)

  // degree + dinv
  k_init_deg<<<gN, 256, 0, stream>>>(dinv);
  k_count<<<gE, 256, 0, stream>>>(dst, dinv);
  k_rsqrt<<<gN, 256, 0, stream>>>(dinv);

  // layer 1
  k_gemm128<<<gRow, 256, 0, stream>>>(x, W1, buf0, NN);
  k_init_agg<<<gNode4, 256, 0, stream>>>(buf1, buf0, dinv);
  k_scatter<<<gScat, 256, 0, stream>>>(buf0, buf1, dinv, src, dst);
  k_finish<<<gNode4, 256, 0, stream>>>(buf1, b1);

  // layer 2
  k_gemm128<<<gRow, 256, 0, stream>>>(buf1, W2, buf0, NN);
  k_init_agg<<<gNode4, 256, 0, stream>>>(buf1, buf0, dinv);
  k_scatter<<<gScat, 256, 0, stream>>>(buf0, buf1, dinv, src, dst);
  k_finish<<<gNode4, 256, 0, stream>>>(buf1, b2);

  // edge MLP
  k_edge_mlp<<<gMlp, 256, 0, stream>>>(buf1, src, dst, Wm1, bm1, Wm2, bm2, out);
}

// Round 2
// 1643.733 us; speedup vs baseline: 2.5517x; 2.5517x over previous
//
#include <hip/hip_runtime.h>
#include <math.h>

#define NN 100000
#define NE 1600000
#define NB 391  // ceil(NN/256)

typedef __attribute__((ext_vector_type(8))) short bf16x8;
typedef __attribute__((ext_vector_type(4))) float f32x4;

__device__ inline unsigned short f2bf(float f) {
  unsigned int u = __float_as_uint(f);
  u = u + 0x7fffu + ((u >> 16) & 1u);
  return (unsigned short)(u >> 16);
}
__device__ inline float bf2f(unsigned short h) {
  return __uint_as_float(((unsigned int)h) << 16);
}

// ---------------- CSR build ----------------
__global__ __launch_bounds__(256) void k_zero(int* __restrict__ deg) {
  int i = blockIdx.x * 256 + threadIdx.x;
  if (i < NN) deg[i] = 0;
}

__global__ __launch_bounds__(256) void k_hist(const int* __restrict__ dst, int* __restrict__ deg) {
  int e = blockIdx.x * 256 + threadIdx.x;
  if (e < NE) atomicAdd(&deg[dst[e]], 1);
}

// block-level exclusive scan: tmp[i] = exclusive-in-block, bsum[b] = block total
__global__ __launch_bounds__(256) void k_scan1(const int* __restrict__ deg, int* __restrict__ tmp,
                                               int* __restrict__ bsum) {
  __shared__ int wsum[4];
  int i = blockIdx.x * 256 + threadIdx.x;
  int v = (i < NN) ? deg[i] : 0;
  int x = v;
#pragma unroll
  for (int d = 1; d < 64; d <<= 1) {
    int y = __shfl_up(x, d);
    if ((threadIdx.x & 63) >= d) x += y;
  }
  if ((threadIdx.x & 63) == 63) wsum[threadIdx.x >> 6] = x;
  __syncthreads();
  int add = 0;
  for (int w = 0; w < (threadIdx.x >> 6); ++w) add += wsum[w];
  int incl = x + add;
  if (i < NN) tmp[i] = incl - v;
  if (threadIdx.x == 255) bsum[blockIdx.x] = incl;
}

__global__ void k_scan2(const int* __restrict__ bsum, int* __restrict__ boff) {
  if (threadIdx.x == 0) {
    int run = 0;
    for (int b = 0; b < NB; ++b) { boff[b] = run; run += bsum[b]; }
  }
}

// rs = global exclusive scan; cursor = rs copy; dinv = rsqrt(deg+1)
__global__ __launch_bounds__(256) void k_scan3(const int* __restrict__ deg, int* __restrict__ tmp,
                                               const int* __restrict__ boff, int* __restrict__ rs,
                                               float* __restrict__ dinv) {
  int i = blockIdx.x * 256 + threadIdx.x;
  if (i < NN) {
    int v = tmp[i] + boff[blockIdx.x];
    rs[i] = v;
    tmp[i] = v;  // tmp doubles as atomic cursor for k_fill
    dinv[i] = rsqrtf((float)(deg[i] + 1));
  }
  if (i == 0) rs[NN] = NE;
}

__global__ __launch_bounds__(256) void k_fill(const int* __restrict__ src, const int* __restrict__ dst,
                                              int* __restrict__ cursor, int* __restrict__ srcs) {
  int e = blockIdx.x * 256 + threadIdx.x;
  if (e < NE) {
    int p = atomicAdd(&cursor[dst[e]], 1);
    srcs[p] = src[e];
  }
}

// ---------------- GEMM fp32 -> bf16 out: Y[r][c] = sum_k X[r][k]*W[k][c], K=C=128 ----------------
__global__ __launch_bounds__(256) void k_gemm128(const float* __restrict__ X, const float* __restrict__ W,
                                                 unsigned short* __restrict__ Y, int nrows) {
  __shared__ float Wl[128 * 128];
  const float4* W4 = (const float4*)W;
  float4* Wl4 = (float4*)Wl;
#pragma unroll
  for (int i = 0; i < 16; ++i) Wl4[threadIdx.x + i * 256] = W4[threadIdx.x + i * 256];
  __syncthreads();

  const int tc = threadIdx.x & 15;
  const int tr = threadIdx.x >> 4;
  const int r0 = blockIdx.x * 64 + tr * 4;
  const int c0 = tc * 8;

  float acc[4][8];
#pragma unroll
  for (int i = 0; i < 4; ++i)
#pragma unroll
    for (int j = 0; j < 8; ++j) acc[i][j] = 0.f;

  for (int k0 = 0; k0 < 128; k0 += 4) {
    float4 xv[4];
#pragma unroll
    for (int i = 0; i < 4; ++i) {
      int r = r0 + i;
      xv[i] = (r < nrows) ? *(const float4*)(X + (size_t)r * 128 + k0)
                          : make_float4(0.f, 0.f, 0.f, 0.f);
    }
#pragma unroll
    for (int kk = 0; kk < 4; ++kk) {
      float4 wa = *(const float4*)(Wl + (k0 + kk) * 128 + c0);
      float4 wb = *(const float4*)(Wl + (k0 + kk) * 128 + c0 + 4);
      float wv[8] = {wa.x, wa.y, wa.z, wa.w, wb.x, wb.y, wb.z, wb.w};
#pragma unroll
      for (int i = 0; i < 4; ++i) {
        float xs = reinterpret_cast<const float*>(&xv[i])[kk];
#pragma unroll
        for (int j = 0; j < 8; ++j) acc[i][j] = fmaf(xs, wv[j], acc[i][j]);
      }
    }
  }

#pragma unroll
  for (int i = 0; i < 4; ++i) {
    int r = r0 + i;
    if (r < nrows) {
      unsigned short h[8];
#pragma unroll
      for (int j = 0; j < 8; ++j) h[j] = f2bf(acc[i][j]);
      *(uint4*)(Y + (size_t)r * 128 + c0) = *(const uint4*)h;
    }
  }
}

// ---------------- fused aggregate: out[d] = relu(dinv[d]*(sum_s dinv[s]*T[s] + dinv[d]*T[d]) + b)
// one wave per node; T is bf16 [NN][128]; writes fp32 (outF) or bf16 (outB)
__global__ __launch_bounds__(256) void k_agg(const unsigned short* __restrict__ T,
                                             const int* __restrict__ rs, const int* __restrict__ srcs,
                                             const float* __restrict__ dinv, const float* __restrict__ bias,
                                             float* __restrict__ outF, unsigned short* __restrict__ outB) {
  int node = blockIdx.x * 4 + (threadIdx.x >> 6);
  if (node >= NN) return;
  int lane = threadIdx.x & 63;
  int beg = rs[node], end = rs[node + 1];
  float dn = dinv[node];

  unsigned int sv = *(const unsigned int*)(T + (size_t)node * 128 + lane * 2);
  float ax = dn * bf2f((unsigned short)(sv & 0xffff));
  float ay = dn * bf2f((unsigned short)(sv >> 16));

  for (int j = beg; j < end; ++j) {
    int s = srcs[j];
    float wsc = dinv[s];
    unsigned int hv = *(const unsigned int*)(T + (size_t)s * 128 + lane * 2);
    ax = fmaf(wsc, bf2f((unsigned short)(hv & 0xffff)), ax);
    ay = fmaf(wsc, bf2f((unsigned short)(hv >> 16)), ay);
  }

  float2 bb = *(const float2*)(bias + lane * 2);
  float ox = fmaxf(fmaf(dn, ax, bb.x), 0.f);
  float oy = fmaxf(fmaf(dn, ay, bb.y), 0.f);
  if (outB) {
    unsigned int pv = (unsigned int)f2bf(ox) | ((unsigned int)f2bf(oy) << 16);
    *(unsigned int*)(outB + (size_t)node * 128 + lane * 2) = pv;
  } else {
    *(float2*)(outF + (size_t)node * 128 + lane * 2) = make_float2(ox, oy);
  }
}

// ---------------- Wm1 -> B-fragment layout (bf16) ----------------
// WTf[((f*8+t)*64+lane)*8 + u] = Wm1[k][n], n = f*16+(lane&15), k = t*32+(lane>>4)*8+u
__global__ __launch_bounds__(256) void k_prep_wt(const float* __restrict__ Wm1, unsigned short* __restrict__ WTf) {
  int idx = blockIdx.x * 256 + threadIdx.x;  // 0..32767
  int u = idx & 7;
  int lane = (idx >> 3) & 63;
  int ft = idx >> 9;
  int t = ft & 7, f = ft >> 3;
  int n = f * 16 + (lane & 15);
  int k = t * 32 + (lane >> 4) * 8 + u;
  WTf[idx] = f2bf(Wm1[(size_t)k * 128 + n]);
}

// ---------------- edge MLP via MFMA ----------------
// per wave: 16 edges x 128 cols, K=256 (src feat 128 | dst feat 128). 8 waves/block, persistent.
__global__ __launch_bounds__(512, 4) void k_mlp(const unsigned short* __restrict__ hb,
                                                const int* __restrict__ src, const int* __restrict__ dst,
                                                const unsigned short* __restrict__ WTf,
                                                const float* __restrict__ bm1, const float* __restrict__ Wm2,
                                                const float* __restrict__ bm2, float* __restrict__ out) {
  __shared__ unsigned short WL[32768];  // 64 KB, B-fragments linear
  {
    const uint4* gsrc = (const uint4*)WTf;
    uint4* sdst = (uint4*)WL;
    for (int i = threadIdx.x; i < 4096; i += 512) sdst[i] = gsrc[i];
  }
  __syncthreads();

  const int lane = threadIdx.x & 63;
  const int w = threadIdx.x >> 6;
  const int r = lane & 15, g = lane >> 4;

  float bmv[8], w2v[8];
#pragma unroll
  for (int f = 0; f < 8; ++f) {
    bmv[f] = bm1[f * 16 + r];
    w2v[f] = Wm2[f * 16 + r];
  }
  const float b2 = bm2[0];

  for (int tile = blockIdx.x; tile < NE / 128; tile += gridDim.x) {
    const int e0 = tile * 128 + w * 16;
    const int sn = src[e0 + r];
    const int dn = dst[e0 + r];
    const size_t sb = (size_t)sn * 128 + g * 8;
    const size_t db = (size_t)dn * 128 + g * 8;

    bf16x8 av[8];
#pragma unroll
    for (int t = 0; t < 4; ++t) av[t] = *(const bf16x8*)(hb + sb + t * 32);
#pragma unroll
    for (int t = 0; t < 4; ++t) av[4 + t] = *(const bf16x8*)(hb + db + t * 32);

    f32x4 acc[8];
#pragma unroll
    for (int f = 0; f < 8; ++f) acc[f] = (f32x4){0.f, 0.f, 0.f, 0.f};

#pragma unroll
    for (int t = 0; t < 8; ++t) {
#pragma unroll
      for (int f = 0; f < 8; ++f) {
        bf16x8 bv = *(const bf16x8*)(&WL[((((f << 3) | t) << 6) | lane) << 3]);
        acc[f] = __builtin_amdgcn_mfma_f32_16x16x32_bf16(av[t], bv, acc[f], 0, 0, 0);
      }
    }

    // epilogue: lane holds D rows 4g+j, col f*16+r
    float p0 = 0.f, p1 = 0.f, p2 = 0.f, p3 = 0.f;
#pragma unroll
    for (int f = 0; f < 8; ++f) {
      float z;
      z = fmaxf(acc[f][0] + bmv[f], 0.f); p0 = fmaf(z, w2v[f], p0);
      z = fmaxf(acc[f][1] + bmv[f], 0.f); p1 = fmaf(z, w2v[f], p1);
      z = fmaxf(acc[f][2] + bmv[f], 0.f); p2 = fmaf(z, w2v[f], p2);
      z = fmaxf(acc[f][3] + bmv[f], 0.f); p3 = fmaf(z, w2v[f], p3);
    }
#pragma unroll
    for (int m = 1; m < 16; m <<= 1) {
      p0 += __shfl_xor(p0, m);
      p1 += __shfl_xor(p1, m);
      p2 += __shfl_xor(p2, m);
      p3 += __shfl_xor(p3, m);
    }
    if (r == 0) {
      float4 o;
      o.x = 1.f / (1.f + expf(-(p0 + b2)));
      o.y = 1.f / (1.f + expf(-(p1 + b2)));
      o.z = 1.f / (1.f + expf(-(p2 + b2)));
      o.w = 1.f / (1.f + expf(-(p3 + b2)));
      *(float4*)(out + e0 + g * 4) = o;
    }
  }
}

// ---------------- launch ----------------
extern "C" void kernel_launch(void* const* d_in, const int* in_sizes, int n_in,
                              void* d_out, int out_size, void* d_ws, size_t ws_size,
                              hipStream_t stream) {
  const float* x   = (const float*)d_in[0];
  const int* ei    = (const int*)d_in[1];
  const float* W1  = (const float*)d_in[2];
  const float* b1  = (const float*)d_in[3];
  const float* W2  = (const float*)d_in[4];
  const float* b2  = (const float*)d_in[5];
  const float* Wm1 = (const float*)d_in[6];
  const float* bm1 = (const float*)d_in[7];
  const float* Wm2 = (const float*)d_in[8];
  const float* bm2 = (const float*)d_in[9];
  float* out = (float*)d_out;

  const int* src = ei;
  const int* dst = ei + NE;

  char* ws = (char*)d_ws;
  int*   deg    = (int*)(ws + 0);                 // 400,000
  int*   rs     = (int*)(ws + 400128);            // 400,004
  int*   cursor = (int*)(ws + 800256);            // 400,000 (also scan tmp)
  float* dinv   = (float*)(ws + 1200256);         // 400,000
  int*   bsum   = (int*)(ws + 1600256);           // 1,564
  int*   boff   = (int*)(ws + 1601920);           // 1,564
  unsigned short* WTf  = (unsigned short*)(ws + 1603584);   // 65,536
  int*   srcs   = (int*)(ws + 1669120);           // 6,400,000
  unsigned short* bufT = (unsigned short*)(ws + 8069120);   // 25,600,000 (bf16 GEMM out)
  float* bufH   = (float*)(ws + 33669120);        // 51,200,000 (fp32 h1)
  unsigned short* hb   = (unsigned short*)bufH;   // bf16 h2 reuses bufH space

  const int gN = NB;                 // 391
  const int gE = (NE + 255) / 256;   // 6250
  const int gRow = (NN + 63) / 64;   // 1563
  const int gAgg = NN / 4;           // 25000
  const int gMlp = 512;

  // CSR build (once; reused by both layers)
  k_zero<<<gN, 256, 0, stream>>>(deg);
  k_hist<<<gE, 256, 0, stream>>>(dst, deg);
  k_scan1<<<gN, 256, 0, stream>>>(deg, cursor, bsum);
  k_scan2<<<1, 64, 0, stream>>>(bsum, boff);
  k_scan3<<<gN, 256, 0, stream>>>(deg, cursor, boff, rs, dinv);
  k_fill<<<gE, 256, 0, stream>>>(src, dst, cursor, srcs);
  k_prep_wt<<<128, 256, 0, stream>>>(Wm1, WTf);

  // layer 1: gemm(x,W1)->bufT(bf16); agg->bufH(fp32)
  k_gemm128<<<gRow, 256, 0, stream>>>(x, W1, bufT, NN);
  k_agg<<<gAgg, 256, 0, stream>>>(bufT, rs, srcs, dinv, b1, bufH, (unsigned short*)0);

  // layer 2: gemm(h1,W2)->bufT(bf16); agg->hb(bf16)
  k_gemm128<<<gRow, 256, 0, stream>>>(bufH, W2, bufT, NN);
  k_agg<<<gAgg, 256, 0, stream>>>(bufT, rs, srcs, dinv, b2, (float*)0, hb);

  // edge MLP (MFMA)
  k_mlp<<<gMlp, 512, 0, stream>>>(hb, src, dst, WTf, bm1, Wm2, bm2, out);
}

// Round 3
// 981.083 us; speedup vs baseline: 4.2752x; 1.6754x over previous
//
#include <hip/hip_runtime.h>
#include <math.h>

#define NN 100000
#define NE 1600000
#define NB 391  // ceil(NN/256)

__device__ inline unsigned short f2bf(float f) {
  unsigned int u = __float_as_uint(f);
  u = u + 0x7fffu + ((u >> 16) & 1u);
  return (unsigned short)(u >> 16);
}
__device__ inline float bf2f(unsigned short h) {
  return __uint_as_float(((unsigned int)h) << 16);
}

// ---------------- CSR build ----------------
__global__ __launch_bounds__(256) void k_zero(int* __restrict__ deg) {
  int i = blockIdx.x * 256 + threadIdx.x;
  if (i < NN) deg[i] = 0;
}

__global__ __launch_bounds__(256) void k_hist(const int* __restrict__ dst, int* __restrict__ deg) {
  int e = blockIdx.x * 256 + threadIdx.x;
  if (e < NE) atomicAdd(&deg[dst[e]], 1);
}

__global__ __launch_bounds__(256) void k_scan1(const int* __restrict__ deg, int* __restrict__ tmp,
                                               int* __restrict__ bsum) {
  __shared__ int wsum[4];
  int i = blockIdx.x * 256 + threadIdx.x;
  int v = (i < NN) ? deg[i] : 0;
  int x = v;
#pragma unroll
  for (int d = 1; d < 64; d <<= 1) {
    int y = __shfl_up(x, d);
    if ((threadIdx.x & 63) >= d) x += y;
  }
  if ((threadIdx.x & 63) == 63) wsum[threadIdx.x >> 6] = x;
  __syncthreads();
  int add = 0;
  for (int w = 0; w < (threadIdx.x >> 6); ++w) add += wsum[w];
  int incl = x + add;
  if (i < NN) tmp[i] = incl - v;
  if (threadIdx.x == 255) bsum[blockIdx.x] = incl;
}

__global__ void k_scan2(const int* __restrict__ bsum, int* __restrict__ boff) {
  if (threadIdx.x == 0) {
    int run = 0;
    for (int b = 0; b < NB; ++b) { boff[b] = run; run += bsum[b]; }
  }
}

__global__ __launch_bounds__(256) void k_scan3(const int* __restrict__ deg, int* __restrict__ tmp,
                                               const int* __restrict__ boff, int* __restrict__ rs,
                                               float* __restrict__ dinv) {
  int i = blockIdx.x * 256 + threadIdx.x;
  if (i < NN) {
    int v = tmp[i] + boff[blockIdx.x];
    rs[i] = v;
    tmp[i] = v;  // becomes the atomic cursor for k_fill
    dinv[i] = rsqrtf((float)(deg[i] + 1));
  }
  if (i == 0) rs[NN] = NE;
}

__global__ __launch_bounds__(256) void k_fill(const int* __restrict__ src, const int* __restrict__ dst,
                                              int* __restrict__ cursor, int2* __restrict__ sei) {
  int e = blockIdx.x * 256 + threadIdx.x;
  if (e < NE) {
    int p = atomicAdd(&cursor[dst[e]], 1);
    sei[p] = make_int2(src[e], e);
  }
}

// ---------------- GEMM fp32 in -> bf16 out: Y = X @ W, K=C=128 ----------------
__global__ __launch_bounds__(256) void k_gemm128(const float* __restrict__ X, const float* __restrict__ W,
                                                 unsigned short* __restrict__ Y, int nrows) {
  __shared__ float Wl[128 * 128];
  const float4* W4 = (const float4*)W;
  float4* Wl4 = (float4*)Wl;
#pragma unroll
  for (int i = 0; i < 16; ++i) Wl4[threadIdx.x + i * 256] = W4[threadIdx.x + i * 256];
  __syncthreads();

  const int tc = threadIdx.x & 15;
  const int tr = threadIdx.x >> 4;
  const int r0 = blockIdx.x * 64 + tr * 4;
  const int c0 = tc * 8;

  float acc[4][8];
#pragma unroll
  for (int i = 0; i < 4; ++i)
#pragma unroll
    for (int j = 0; j < 8; ++j) acc[i][j] = 0.f;

  for (int k0 = 0; k0 < 128; k0 += 4) {
    float4 xv[4];
#pragma unroll
    for (int i = 0; i < 4; ++i) {
      int r = r0 + i;
      xv[i] = (r < nrows) ? *(const float4*)(X + (size_t)r * 128 + k0)
                          : make_float4(0.f, 0.f, 0.f, 0.f);
    }
#pragma unroll
    for (int kk = 0; kk < 4; ++kk) {
      float4 wa = *(const float4*)(Wl + (k0 + kk) * 128 + c0);
      float4 wb = *(const float4*)(Wl + (k0 + kk) * 128 + c0 + 4);
      float wv[8] = {wa.x, wa.y, wa.z, wa.w, wb.x, wb.y, wb.z, wb.w};
#pragma unroll
      for (int i = 0; i < 4; ++i) {
        float xs = reinterpret_cast<const float*>(&xv[i])[kk];
#pragma unroll
        for (int j = 0; j < 8; ++j) acc[i][j] = fmaf(xs, wv[j], acc[i][j]);
      }
    }
  }

#pragma unroll
  for (int i = 0; i < 4; ++i) {
    int r = r0 + i;
    if (r < nrows) {
      unsigned short h[8];
#pragma unroll
      for (int j = 0; j < 8; ++j) h[j] = f2bf(acc[i][j]);
      *(uint4*)(Y + (size_t)r * 128 + c0) = *(const uint4*)h;
    }
  }
}

// ---------------- GEMM bf16 in -> bf16 out: Y = X @ W, K=C=128 ----------------
__global__ __launch_bounds__(256) void k_gemm128b(const unsigned short* __restrict__ X,
                                                  const float* __restrict__ W,
                                                  unsigned short* __restrict__ Y, int nrows) {
  __shared__ float Wl[128 * 128];
  const float4* W4 = (const float4*)W;
  float4* Wl4 = (float4*)Wl;
#pragma unroll
  for (int i = 0; i < 16; ++i) Wl4[threadIdx.x + i * 256] = W4[threadIdx.x + i * 256];
  __syncthreads();

  const int tc = threadIdx.x & 15;
  const int tr = threadIdx.x >> 4;
  const int r0 = blockIdx.x * 64 + tr * 4;
  const int c0 = tc * 8;

  float acc[4][8];
#pragma unroll
  for (int i = 0; i < 4; ++i)
#pragma unroll
    for (int j = 0; j < 8; ++j) acc[i][j] = 0.f;

  for (int k0 = 0; k0 < 128; k0 += 8) {
    uint4 xv[4];
#pragma unroll
    for (int i = 0; i < 4; ++i) {
      int r = r0 + i;
      xv[i] = (r < nrows) ? *(const uint4*)(X + (size_t)r * 128 + k0)
                          : make_uint4(0u, 0u, 0u, 0u);
    }
#pragma unroll
    for (int kk = 0; kk < 8; ++kk) {
      float4 wa = *(const float4*)(Wl + (k0 + kk) * 128 + c0);
      float4 wb = *(const float4*)(Wl + (k0 + kk) * 128 + c0 + 4);
      float wv[8] = {wa.x, wa.y, wa.z, wa.w, wb.x, wb.y, wb.z, wb.w};
#pragma unroll
      for (int i = 0; i < 4; ++i) {
        const unsigned short* px = (const unsigned short*)&xv[i];
        float xs = bf2f(px[kk]);
#pragma unroll
        for (int j = 0; j < 8; ++j) acc[i][j] = fmaf(xs, wv[j], acc[i][j]);
      }
    }
  }

#pragma unroll
  for (int i = 0; i < 4; ++i) {
    int r = r0 + i;
    if (r < nrows) {
      unsigned short h[8];
#pragma unroll
      for (int j = 0; j < 8; ++j) h[j] = f2bf(acc[i][j]);
      *(uint4*)(Y + (size_t)r * 128 + c0) = *(const uint4*)h;
    }
  }
}

// ---------------- fused aggregate: out[d] = relu(dinv[d]*(sum_s dinv[s]*T[s] + dinv[d]*T[d]) + b)
__global__ __launch_bounds__(256) void k_agg(const unsigned short* __restrict__ T,
                                             const int* __restrict__ rs, const int2* __restrict__ sei,
                                             const float* __restrict__ dinv, const float* __restrict__ bias,
                                             float* __restrict__ outF, unsigned short* __restrict__ outB) {
  int node = blockIdx.x * 4 + (threadIdx.x >> 6);
  if (node >= NN) return;
  int lane = threadIdx.x & 63;
  int beg = rs[node], end = rs[node + 1];
  float dn = dinv[node];

  unsigned int sv = *(const unsigned int*)(T + (size_t)node * 128 + lane * 2);
  float ax = dn * bf2f((unsigned short)(sv & 0xffff));
  float ay = dn * bf2f((unsigned short)(sv >> 16));

  for (int j = beg; j < end; ++j) {
    int s = sei[j].x;
    float wsc = dinv[s];
    unsigned int hv = *(const unsigned int*)(T + (size_t)s * 128 + lane * 2);
    ax = fmaf(wsc, bf2f((unsigned short)(hv & 0xffff)), ax);
    ay = fmaf(wsc, bf2f((unsigned short)(hv >> 16)), ay);
  }

  float2 bb = *(const float2*)(bias + lane * 2);
  float ox = fmaxf(fmaf(dn, ax, bb.x), 0.f);
  float oy = fmaxf(fmaf(dn, ay, bb.y), 0.f);
  if (outB) {
    unsigned int pv = (unsigned int)f2bf(ox) | ((unsigned int)f2bf(oy) << 16);
    *(unsigned int*)(outB + (size_t)node * 128 + lane * 2) = pv;
  } else {
    *(float2*)(outF + (size_t)node * 128 + lane * 2) = make_float2(ox, oy);
  }
}

// ---------------- edge epilogue: out[eid] = sigmoid(relu(u[s]+v[d]+bm1).Wm2 + b2) ----------------
// one wave per dst node; v row cached in regs; u[s] gathered coalesced (256 B/edge)
__global__ __launch_bounds__(256) void k_edge(const unsigned short* __restrict__ u,
                                              const unsigned short* __restrict__ v,
                                              const int* __restrict__ rs, const int2* __restrict__ sei,
                                              const float* __restrict__ bm1, const float* __restrict__ Wm2,
                                              const float* __restrict__ bm2, float* __restrict__ out) {
  int node = blockIdx.x * 4 + (threadIdx.x >> 6);
  if (node >= NN) return;
  int lane = threadIdx.x & 63;
  int beg = rs[node], end = rs[node + 1];
  if (beg >= end) return;

  unsigned int vv = *(const unsigned int*)(v + (size_t)node * 128 + lane * 2);
  float2 bmv = *(const float2*)(bm1 + lane * 2);
  float vb0 = bf2f((unsigned short)(vv & 0xffff)) + bmv.x;
  float vb1 = bf2f((unsigned short)(vv >> 16)) + bmv.y;
  float2 w2 = *(const float2*)(Wm2 + lane * 2);
  float b2 = bm2[0];

  int j = beg;
  for (; j + 2 <= end; j += 2) {
    int2 ea = sei[j];
    int2 eb = sei[j + 1];
    unsigned int ua = *(const unsigned int*)(u + (size_t)ea.x * 128 + lane * 2);
    unsigned int ub = *(const unsigned int*)(u + (size_t)eb.x * 128 + lane * 2);
    float za0 = fmaxf(bf2f((unsigned short)(ua & 0xffff)) + vb0, 0.f);
    float za1 = fmaxf(bf2f((unsigned short)(ua >> 16)) + vb1, 0.f);
    float zb0 = fmaxf(bf2f((unsigned short)(ub & 0xffff)) + vb0, 0.f);
    float zb1 = fmaxf(bf2f((unsigned short)(ub >> 16)) + vb1, 0.f);
    float pa = fmaf(za0, w2.x, za1 * w2.y);
    float pb = fmaf(zb0, w2.x, zb1 * w2.y);
#pragma unroll
    for (int m = 1; m < 64; m <<= 1) {
      pa += __shfl_xor(pa, m);
      pb += __shfl_xor(pb, m);
    }
    if (lane == 0) {
      out[ea.y] = 1.f / (1.f + expf(-(pa + b2)));
      out[eb.y] = 1.f / (1.f + expf(-(pb + b2)));
    }
  }
  if (j < end) {
    int2 ea = sei[j];
    unsigned int ua = *(const unsigned int*)(u + (size_t)ea.x * 128 + lane * 2);
    float za0 = fmaxf(bf2f((unsigned short)(ua & 0xffff)) + vb0, 0.f);
    float za1 = fmaxf(bf2f((unsigned short)(ua >> 16)) + vb1, 0.f);
    float pa = fmaf(za0, w2.x, za1 * w2.y);
#pragma unroll
    for (int m = 1; m < 64; m <<= 1) pa += __shfl_xor(pa, m);
    if (lane == 0) out[ea.y] = 1.f / (1.f + expf(-(pa + b2)));
  }
}

// ---------------- launch ----------------
extern "C" void kernel_launch(void* const* d_in, const int* in_sizes, int n_in,
                              void* d_out, int out_size, void* d_ws, size_t ws_size,
                              hipStream_t stream) {
  const float* x   = (const float*)d_in[0];
  const int* ei    = (const int*)d_in[1];
  const float* W1  = (const float*)d_in[2];
  const float* b1  = (const float*)d_in[3];
  const float* W2  = (const float*)d_in[4];
  const float* b2  = (const float*)d_in[5];
  const float* Wm1 = (const float*)d_in[6];
  const float* bm1 = (const float*)d_in[7];
  const float* Wm2 = (const float*)d_in[8];
  const float* bm2 = (const float*)d_in[9];
  float* out = (float*)d_out;

  const int* src = ei;
  const int* dst = ei + NE;

  char* ws = (char*)d_ws;
  int*   deg    = (int*)(ws + 0x0);        // 400,000 B
  int*   rs     = (int*)(ws + 0x80000);    // 400,004 B
  int*   cursor = (int*)(ws + 0x100000);   // 400,000 B
  float* dinv   = (float*)(ws + 0x180000); // 400,000 B
  int*   bsum   = (int*)(ws + 0x200000);   // 1,564 B
  int*   boff   = (int*)(ws + 0x210000);   // 1,564 B
  int2*  sei    = (int2*)(ws + 0x400000);  // 12,800,000 B
  unsigned short* bufT = (unsigned short*)(ws + 0x1100000);  // 25.6 MB (bf16 gemm out; later u)
  float* bufH   = (float*)(ws + 0x2A00000);                  // 51.2 MB (fp32 h1; later hb + v)
  unsigned short* hb   = (unsigned short*)bufH;              // bf16 h2 (first 25.6 MB of bufH)
  unsigned short* ubuf = bufT;                               // u bf16
  unsigned short* vbuf = (unsigned short*)((char*)bufH + 25600000);  // v bf16

  const int gN = NB;
  const int gE = (NE + 255) / 256;
  const int gRow = (NN + 63) / 64;
  const int gAgg = (NN + 3) / 4;

  // CSR build
  k_zero<<<gN, 256, 0, stream>>>(deg);
  k_hist<<<gE, 256, 0, stream>>>(dst, deg);
  k_scan1<<<gN, 256, 0, stream>>>(deg, cursor, bsum);
  k_scan2<<<1, 64, 0, stream>>>(bsum, boff);
  k_scan3<<<gN, 256, 0, stream>>>(deg, cursor, boff, rs, dinv);
  k_fill<<<gE, 256, 0, stream>>>(src, dst, cursor, sei);

  // layer 1: t1 = x@W1 (bf16); h1 = agg (fp32)
  k_gemm128<<<gRow, 256, 0, stream>>>(x, W1, bufT, NN);
  k_agg<<<gAgg, 256, 0, stream>>>(bufT, rs, sei, dinv, b1, bufH, (unsigned short*)0);

  // layer 2: t2 = h1@W2 (bf16); h2 = agg (bf16)
  k_gemm128<<<gRow, 256, 0, stream>>>(bufH, W2, bufT, NN);
  k_agg<<<gAgg, 256, 0, stream>>>(bufT, rs, sei, dinv, b2, (float*)0, hb);

  // u = h2 @ Wm1_top, v = h2 @ Wm1_bot
  k_gemm128b<<<gRow, 256, 0, stream>>>(hb, Wm1, ubuf, NN);
  k_gemm128b<<<gRow, 256, 0, stream>>>(hb, Wm1 + 128 * 128, vbuf, NN);

  // edge epilogue
  k_edge<<<gAgg, 256, 0, stream>>>(ubuf, vbuf, rs, sei, bm1, Wm2, bm2, out);
}